// Round 7
// baseline (141.681 us; speedup 1.0000x reference)
//
#include <hip/hip_runtime.h>

// Router: out[t] = x[t] @ W[split[t]] + b[split[t]]
// N=262144, D=128, E=8. fp32 in/out, bf16 MFMA.
// R7: persistent 1-block/CU, 4 windows x 256 tokens, 2-deep register pipeline.
// Per iter: issue xv(t+1) -> lookahead meta -> compute(t) -> scatter(t+1).
// Raw s_barrier + lgkmcnt(0) only (no vmcnt drain): loads of t+1 and stores
// of t stay in flight across the barrier. All in-loop global traffic is
// register-mediated so the compiler emits counted vmcnt waits at use.

typedef __bf16 bf16x8 __attribute__((ext_vector_type(8)));
typedef unsigned short u16x8 __attribute__((ext_vector_type(8)));
typedef float f32x4 __attribute__((ext_vector_type(4)));

__device__ __forceinline__ unsigned short f2bf(float f) {
    unsigned u = __builtin_bit_cast(unsigned, f);
    u += 0x7FFFu + ((u >> 16) & 1u);   // RNE
    return (unsigned short)(u >> 16);
}
__device__ __forceinline__ unsigned pack2(float a, float b) {
    return (unsigned)f2bf(a) | ((unsigned)f2bf(b) << 16);
}

// Transpose + convert W[e][f][g] (f32) -> Wt[e][g][f] (bf16).
__global__ void k_wt(const float* __restrict__ W, unsigned short* __restrict__ Wt) {
    __shared__ float T[16][132];
    int e = blockIdx.x >> 3;
    int g0 = (blockIdx.x & 7) << 4;
    const float* We = W + e * 128 * 128;
    #pragma unroll
    for (int i = 0; i < 2; ++i) {
        int idx = i * 256 + threadIdx.x;
        int f = idx >> 2, q = idx & 3;
        float4 v = *(const float4*)(We + f * 128 + g0 + q * 4);
        T[q * 4 + 0][f] = v.x; T[q * 4 + 1][f] = v.y;
        T[q * 4 + 2][f] = v.z; T[q * 4 + 3][f] = v.w;
    }
    __syncthreads();
    int g = threadIdx.x >> 4, fc = threadIdx.x & 15;
    u16x8 o;
    #pragma unroll
    for (int j = 0; j < 8; ++j) o[j] = f2bf(T[g][fc * 8 + j]);
    *(u16x8*)(Wt + ((e * 128 + g0 + g) * 128 + fc * 8)) = o;
}

#define NTOK 256       // tokens per window
#define GRID 256       // persistent blocks, 1 per CU

__global__ __launch_bounds__(512, 2) void k_fused(
    const float* __restrict__ x, const int* __restrict__ split,
    const float* __restrict__ bias, const unsigned short* __restrict__ Wt,
    float* __restrict__ out, int iters) {

    __shared__ unsigned short A[2][NTOK * 128];   // 2 x 64 KB bf16, bucketed+swizzled
    __shared__ int sSplit[4 * NTOK];              // all 4 windows' split
    __shared__ int destR[4][NTOK];                // token -> bucket slot (ring)
    __shared__ int trowR[4][NTOK];                // bucket slot -> token (ring)
    __shared__ int wcntR[4][4][8];                // per-wave expert counts (ring)
    __shared__ int cntR[4][8], startR[4][8];

    const int tid = threadIdx.x;
    const int lane = tid & 63, w = tid >> 6;
    const int l15 = lane & 15, lq = lane >> 4;
    const int win0 = (int)blockIdx.x * iters;

    // ---- preload B fragments + bias: all 8 experts, this wave's 16 cols ----
    bf16x8 bf_[8][4];
    float bv_[8];
    #pragma unroll
    for (int ee = 0; ee < 8; ++ee) {
        #pragma unroll
        for (int kk = 0; kk < 4; ++kk)
            bf_[ee][kk] = *(const bf16x8*)(Wt + (ee * 128 + w * 16 + l15) * 128 + kk * 32 + lq * 8);
        bv_[ee] = bias[ee * 128 + w * 16 + l15];
    }

    auto BARRIER = [&]() {
        asm volatile("s_waitcnt lgkmcnt(0)" ::: "memory");
        __builtin_amdgcn_s_barrier();
    };

    // per-wave expert counts for local window lw -> wcntR
    auto BALLOT = [&](int lw) {
        if (tid < NTOK) {
            int e = sSplit[lw * NTOK + tid];
            #pragma unroll
            for (int ee = 0; ee < 8; ++ee) {
                unsigned long long m = __ballot(e == ee);
                if (lane == ee) wcntR[lw & 3][w][ee] = (int)__popcll(m);
            }
        }
    };

    // scans for window lw: dest/trow/cnt/start (wcntR[lw] must be visible)
    auto SCAN = [&](int lw) {
        if (tid < NTOK) {
            int e = sSplit[lw * NTOK + tid];
            unsigned long long below = (1ull << lane) - 1;
            int rank = 0;
            #pragma unroll
            for (int ee = 0; ee < 8; ++ee) {
                unsigned long long m = __ballot(e == ee);
                if (e == ee) rank = (int)__popcll(m & below);
            }
            int r = lw & 3;
            int sE = 0, woff = 0, run = 0, myTot = 0, myStart = 0;
            #pragma unroll
            for (int ee = 0; ee < 8; ++ee) {
                int c0 = wcntR[r][0][ee], c1 = wcntR[r][1][ee];
                int c2 = wcntR[r][2][ee], c3 = wcntR[r][3][ee];
                int tot = c0 + c1 + c2 + c3;
                int wo = (w > 0 ? c0 : 0) + (w > 1 ? c1 : 0) + (w > 2 ? c2 : 0);
                if (ee == e)    { sE = run; woff = wo; }
                if (ee == lane) { myTot = tot; myStart = run; }
                run += tot;
            }
            int slot = sE + woff + rank;
            destR[r][tid] = slot;
            trowR[r][slot] = tid;
            if (w == 0 && lane < 8) { cntR[r][lane] = myTot; startR[r][lane] = myStart; }
        }
    };

    float4 xv[16];

    // scatter xv (window lw) into A[buf], bucketed + chunk-XOR swizzled
    auto SCATTER = [&](int lw, int buf) {
        int r = lw & 3;
        #pragma unroll
        for (int rr = 0; rr < 16; ++rr) {
            int c = rr * 512 + tid;          // 16B f32 chunk id (8192/window)
            int row = c >> 5;
            int s = destR[r][row];
            int fc = (c & 31) >> 1, half = c & 1;
            *(uint2*)(&A[buf][s * 128 + ((fc ^ (s & 7)) << 3) + half * 4]) =
                make_uint2(pack2(xv[rr].x, xv[rr].y), pack2(xv[rr].z, xv[rr].w));
        }
    };

    // ---- prologue ----
    {
        const float* xb = x + (long)win0 * NTOK * 128;
        #pragma unroll
        for (int rr = 0; rr < 16; ++rr)
            xv[rr] = *(const float4*)(xb + (rr * 512 + tid) * 4);
    }
    {
        int2 sv = *(const int2*)(split + (long)win0 * NTOK + tid * 2);
        sSplit[tid * 2] = sv.x; sSplit[tid * 2 + 1] = sv.y;
    }
    BARRIER();
    #pragma unroll
    for (int lw = 0; lw < 3; ++lw) BALLOT(lw);
    BARRIER();
    SCAN(0);
    SCAN(1);
    BARRIER();          // dest[0] visible for scatter(0)
    SCATTER(0, 0);      // waits xv(0) here
    BARRIER();          // A[0], trow[0] visible

    // ---- steady state ----
    for (int t = 0; t < iters; ++t) {
        const int win = win0 + t;

        // ph1: issue x loads for window t+1 (fly under ph2+ph3)
        if (t + 1 < iters) {
            const float* xb = x + (long)(win + 1) * NTOK * 128;
            #pragma unroll
            for (int rr = 0; rr < 16; ++rr)
                xv[rr] = *(const float4*)(xb + (rr * 512 + tid) * 4);
        }

        // ph2: lookahead meta (no barrier between these writes and their reads
        // in later iterations — ring buffers + end-of-iter barrier cover it)
        if (t + 3 < iters) BALLOT(t + 3);
        if (t + 2 < iters) SCAN(t + 2);

        // ph3: compute window t from A[t&1]
        {
            const int r = t & 3, buf = t & 1;
            const long tb = (long)win * NTOK;
            #pragma unroll
            for (int ee = 0; ee < 8; ++ee) {
                int cnt = cntR[r][ee], st = startR[r][ee];
                for (int k2 = 0; k2 * 16 < cnt; ++k2) {
                    int rb = st + k2 * 16;
                    int rem = cnt - k2 * 16;
                    int lim = rem < 16 ? rem : 16;
                    int sr = rb + l15; sr = sr < NTOK ? sr : NTOK - 1;
                    f32x4 acc = {0.f, 0.f, 0.f, 0.f};
                    #pragma unroll
                    for (int kk = 0; kk < 4; ++kk) {
                        int fc = kk * 4 + lq;
                        bf16x8 a = *(const bf16x8*)(&A[buf][sr * 128 + ((fc ^ (sr & 7)) << 3)]);
                        acc = __builtin_amdgcn_mfma_f32_16x16x32_bf16(a, bf_[ee][kk], acc, 0, 0, 0);
                    }
                    #pragma unroll
                    for (int rr2 = 0; rr2 < 4; ++rr2) {
                        int ri = lq * 4 + rr2;
                        if (ri < lim) {
                            int tok = trowR[r][rb + ri];
                            out[(tb + tok) * 128 + w * 16 + l15] = acc[rr2] + bv_[ee];
                        }
                    }
                }
            }
        }

        // ph4: scatter window t+1 (the only place xv is waited on)
        if (t + 1 < iters) SCATTER(t + 1, (t + 1) & 1);

        BARRIER();   // lgkmcnt only — stores/loads stay in flight
    }
}

extern "C" void kernel_launch(void* const* d_in, const int* in_sizes, int n_in,
                              void* d_out, int out_size, void* d_ws, size_t ws_size,
                              hipStream_t stream) {
    const float* x     = (const float*)d_in[0];
    const int*   split = (const int*)d_in[1];
    const float* W     = (const float*)d_in[2];
    const float* bias  = (const float*)d_in[3];
    float* out = (float*)d_out;

    int n = in_sizes[1];                      // 262144
    unsigned short* Wt = (unsigned short*)d_ws;   // 8*128*128 bf16 = 256 KB

    int iters = (n / NTOK) / GRID;            // 4

    k_wt<<<64, 256, 0, stream>>>(W, Wt);
    k_fused<<<GRID, 512, 0, stream>>>(x, split, bias, Wt, out, iters);
}